// Round 16
// baseline (3238.233 us; speedup 1.0000x reference)
//
#include <hip/hip_runtime.h>
#include <stdint.h>

#define N_SEQ 16384
#define T_LEN 16
#define E_DIM 256
#define H_DIM 256
#define K_DIM 512
#define B_SAMP 128
#define V_SIZE 10000
#define NBLK_LENS (N_SEQ / 256)

typedef __bf16 bf16x8 __attribute__((ext_vector_type(8)));
typedef float  f32x4  __attribute__((ext_vector_type(4)));
typedef unsigned short ush;

__device__ __forceinline__ ush f2bf(float x) {
  unsigned int u = __float_as_uint(x);
  u = (u + 0x7fffu + ((u >> 16) & 1u)) >> 16;
  return (ush)u;
}
__device__ __forceinline__ float bf2f(ush v) {
  return __uint_as_float(((unsigned int)v) << 16);
}
__device__ __forceinline__ float sigmoidf_(float x) {
  return 1.0f / (1.0f + __expf(-x));
}
__device__ __forceinline__ float tanhf_(float x) {
  float e = __expf(2.0f * x);
  return 1.0f - 2.0f / (e + 1.0f);
}
__device__ __forceinline__ void glds16(const void* g, const void* l) {
  __builtin_amdgcn_global_load_lds(
      (const __attribute__((address_space(1))) unsigned int*)g,
      (__attribute__((address_space(3))) unsigned int*)l, 16, 0, 0);
}

// ---------------- prep kernels ----------------

// lens + per-block histogram (no global atomics)
__global__ __launch_bounds__(256) void k_lens(const int* __restrict__ tok, int* __restrict__ lens,
                                              int* __restrict__ blockhist) {
  __shared__ int lh[17];
  if (threadIdx.x < 17) lh[threadIdx.x] = 0;
  __syncthreads();
  int n = blockIdx.x * 256 + threadIdx.x;
  const int* r = tok + n * T_LEN;
  int c = 0;
#pragma unroll
  for (int t = 0; t < T_LEN; ++t) c += (r[t] != 0);
  lens[n] = c;
  atomicAdd(&lh[c], 1);  // LDS atomic: cheap
  __syncthreads();
  if (threadIdx.x < 17) blockhist[blockIdx.x * 17 + threadIdx.x] = lh[threadIdx.x];
}

// descending-length bucket starts + per-block bases + cnts[t] = count(len > t)
__global__ void k_offsets(const int* __restrict__ blockhist, int* __restrict__ base,
                          int* __restrict__ cnts) {
  if (threadIdx.x == 0) {
    int tot[17];
    for (int l = 0; l <= 16; ++l) {
      int s = 0;
      for (int b = 0; b < NBLK_LENS; ++b) s += blockhist[b * 17 + l];
      tot[l] = s;
    }
    int start[17];
    int off = 0;
    for (int l = 16; l >= 0; --l) { start[l] = off; off += tot[l]; }
    for (int l = 0; l <= 16; ++l) {
      int run = start[l];
      for (int b = 0; b < NBLK_LENS; ++b) { base[b * 17 + l] = run; run += blockhist[b * 17 + l]; }
    }
    for (int t = 0; t < 16; ++t) {
      int c = 0;
      for (int l = t + 1; l <= 16; ++l) c += tot[l];
      cnts[t] = c;
    }
  }
}

// rank via LDS atomics + per-block base (no global atomic contention)
__global__ __launch_bounds__(256) void k_scatter(const int* __restrict__ lens, const int* __restrict__ base,
                                                 int* __restrict__ perm, int* __restrict__ pinv,
                                                 int* __restrict__ plens) {
  __shared__ int lh[17];
  if (threadIdx.x < 17) lh[threadIdx.x] = 0;
  __syncthreads();
  int n = blockIdx.x * 256 + threadIdx.x;
  int l = lens[n];
  int lr = atomicAdd(&lh[l], 1);
  int pos = base[blockIdx.x * 17 + l] + lr;
  perm[pos] = n;
  pinv[n] = pos;
  plens[pos] = l;
}

// gather form: coalesced writes; tok (1 MB) is L2-resident
__global__ __launch_bounds__(256) void k_tokperm(const int* __restrict__ tok, const int* __restrict__ perm,
                                                 int* __restrict__ tokperm) {
  int id = blockIdx.x * 256 + threadIdx.x;  // < T_LEN * N_SEQ
  int t = id >> 14;                          // N_SEQ = 2^14
  int pos = id & (N_SEQ - 1);
  tokperm[id] = tok[perm[pos] * T_LEN + t];
}

__global__ __launch_bounds__(256) void k_embcvt(const float* __restrict__ emb, ush* __restrict__ out) {
  int i = blockIdx.x * 256 + threadIdx.x;
  out[i] = f2bf(emb[i]);
}

// Permuted weights: wpt[p][k], p = nb*256 + wc*64 + q*16 + jj  <->
// gate-row r = q*256 + (nb*64 + wc*16 + jj);  k<256 -> W_ih[r][k], else W_hh[r][k-256].
__global__ __launch_bounds__(256) void k_wprep(const float* __restrict__ Wih_f, const float* __restrict__ Whh_f,
                                               const float* __restrict__ Wih_b, const float* __restrict__ Whh_b,
                                               ush* __restrict__ wpt_f, ush* __restrict__ wpt_b) {
  int id = blockIdx.x * 256 + threadIdx.x;  // < 2*1024*512
  int dir = id >> 19;
  int rem = id & ((1 << 19) - 1);
  int p = rem >> 9;
  int k = rem & 511;
  int nb = p >> 8, wc = (p >> 6) & 3, q = (p >> 4) & 3, jj = p & 15;
  int r = q * 256 + nb * 64 + wc * 16 + jj;
  const float* Wih = dir ? Wih_b : Wih_f;
  const float* Whh = dir ? Whh_b : Whh_f;
  float v = (k < 256) ? Wih[r * 256 + k] : Whh[r * 256 + (k - 256)];
  ush* o = dir ? wpt_b : wpt_f;
  o[p * 512 + k] = f2bf(v);
}

// ---------------- LSTM step: K=512 fused GEMM + cell update (R15 core, measured best) ----------------
// grid(512,2): mblk = bid.x>>2, nblk = bid.x&3, dir = bid.y. Length-sorted rows;
// active prefix cnts[t] = count(len>t); blocks past it exit. 512 thr / 8 waves (2x4),
// tile 128 rows x 256 pcols, K=512 in 8 chunks of 64; XOR-swizzled LDS (measured
// conflict-free); glds16 staging; 2 barriers/chunk. Parity pooling: NO graduation
// copies; first-active-step c init. R16: cT[j][n] f32 transposed cell state
// (f32x4, full 64B lines, 4x fewer transactions), c/lens/bias prefetched into
// VGPRs before the GEMM, launch_bounds min-waves 6 (3 blocks/CU target).

__global__ __launch_bounds__(512, 6)
void k_step(const ush* __restrict__ embbf, const int* __restrict__ tokperm,
            const int* __restrict__ plens, const int* __restrict__ cnts,
            const ush* __restrict__ wpt_f, const ush* __restrict__ wpt_b,
            const float* __restrict__ bias_f, const float* __restrict__ bias_b,
            const ush* __restrict__ hr_f, ush* __restrict__ hw_f,
            const ush* __restrict__ hr_b, ush* __restrict__ hw_b,
            float* __restrict__ cT_f, float* __restrict__ cT_b,
            int s) {
  const int dir = blockIdx.y;
  const int t = dir ? (15 - s) : s;
  const int cnt = cnts[t];
  const int mblk = blockIdx.x >> 2;
  const int m0 = mblk * 128;
  if (m0 >= cnt) return;

  const int nblk = blockIdx.x & 3;
  const ush* wpt = dir ? wpt_b : wpt_f;
  const float* bias = dir ? bias_b : bias_f;
  const ush* hr = dir ? hr_b : hr_f;
  ush* hw = dir ? hw_b : hw_f;
  float* cT = dir ? cT_b : cT_f;

  __shared__ __align__(128) unsigned char ldsA[128 * 128];  // 16 KB
  __shared__ __align__(128) unsigned char ldsB[256 * 128];  // 32 KB

  const int tid = threadIdx.x;
  const int lane = tid & 63;
  const int w = tid >> 6;
  const int wr = w >> 2;
  const int wc = w & 3;
  const int frow = lane & 15;
  const int fkq = lane >> 4;  // 0..3

  // ---- epilogue prefetch: bias, lens, c (independent of the GEMM; hides latency) ----
  const int j = nblk * 64 + wc * 16 + frow;
  const float b0 = bias[j], b1 = bias[256 + j], b2 = bias[512 + j], b3 = bias[768 + j];
  int4 l4[4];
  f32x4 cv4[4];
#pragma unroll
  for (int fr = 0; fr < 4; ++fr) {
    const int n0 = m0 + wr * 64 + fr * 16 + fkq * 4;
    l4[fr] = *(const int4*)&plens[n0];
    cv4[fr] = *(const f32x4*)&cT[(size_t)j * N_SEQ + n0];
  }

  // ---- staging address precompute (element offsets, fixed per thread) ----
  const int l8 = lane >> 3;        // sub-row within 8-row group
  const int l7 = lane & 7;         // chunk slot in LDS
  const int arow0 = 16 * w + l8;
  const int arow1 = arow0 + 8;
  const int ach0 = l7 ^ (arow0 & 7);
  const int ach1 = l7 ^ (arow1 & 7);
  const unsigned aoffE0 = (unsigned)tokperm[t * N_SEQ + m0 + arow0] * E_DIM + ach0 * 8;
  const unsigned aoffE1 = (unsigned)tokperm[t * N_SEQ + m0 + arow1] * E_DIM + ach1 * 8;
  const unsigned aoffH0 = (unsigned)(m0 + arow0) * H_DIM + ach0 * 8;
  const unsigned aoffH1 = (unsigned)(m0 + arow1) * H_DIM + ach1 * 8;
  unsigned boff[4];
#pragma unroll
  for (int jj = 0; jj < 4; ++jj) {
    const int brow = 32 * w + 8 * jj + l8;
    const int bch = l7 ^ (brow & 7);
    boff[jj] = (unsigned)(nblk * 256 + brow) * K_DIM + bch * 8;
  }

  f32x4 acc[4][4] = {};

  for (int kt = 0; kt < 8; ++kt) {
    const int k0 = kt * 64;
    if (kt < 4) {
      glds16(embbf + aoffE0 + k0, &ldsA[(16 * w) * 128]);
      glds16(embbf + aoffE1 + k0, &ldsA[(16 * w + 8) * 128]);
    } else {
      glds16(hr + aoffH0 + (k0 - E_DIM), &ldsA[(16 * w) * 128]);
      glds16(hr + aoffH1 + (k0 - E_DIM), &ldsA[(16 * w + 8) * 128]);
    }
#pragma unroll
    for (int jj = 0; jj < 4; ++jj)
      glds16(wpt + boff[jj] + k0, &ldsB[(32 * w + 8 * jj) * 128]);
    __syncthreads();
#pragma unroll
    for (int ksub = 0; ksub < 2; ++ksub) {
      bf16x8 av[4], bv[4];
#pragma unroll
      for (int fr = 0; fr < 4; ++fr) {
        const int row = wr * 64 + fr * 16 + frow;
        const int ch = (ksub * 4 + fkq) ^ (row & 7);
        av[fr] = *(const bf16x8*)&ldsA[row * 128 + ch * 16];
      }
#pragma unroll
      for (int fc = 0; fc < 4; ++fc) {
        const int row = wc * 64 + fc * 16 + frow;
        const int ch = (ksub * 4 + fkq) ^ (row & 7);
        bv[fc] = *(const bf16x8*)&ldsB[row * 128 + ch * 16];
      }
#pragma unroll
      for (int fr = 0; fr < 4; ++fr)
#pragma unroll
        for (int fc = 0; fc < 4; ++fc)
          acc[fr][fc] = __builtin_amdgcn_mfma_f32_16x16x32_bf16(av[fr], bv[fc], acc[fr][fc], 0, 0, 0);
    }
    __syncthreads();
  }

  // ---- fused LSTM cell update: fc = gate (i,f,g,o) for hidden unit j; no copies ----
#pragma unroll
  for (int fr = 0; fr < 4; ++fr) {
    const int n0 = m0 + wr * 64 + fr * 16 + fkq * 4;
    const int4 ln = l4[fr];
    const int lmax = max(max(ln.x, ln.y), max(ln.z, ln.w));
    if (t >= lmax) continue;  // whole row-group graduated: no writes
    f32x4 cv = cv4[fr];
    const f32x4 gi = acc[fr][0], gf = acc[fr][1], gg = acc[fr][2], go = acc[fr][3];
#pragma unroll
    for (int r = 0; r < 4; ++r) {
      const int lnv = (r == 0) ? ln.x : (r == 1) ? ln.y : (r == 2) ? ln.z : ln.w;
      if (t < lnv) {
        const float iv = sigmoidf_(gi[r] + b0);
        const float fv = sigmoidf_(gf[r] + b1);
        const float gv = tanhf_(gg[r] + b2);
        const float ov = sigmoidf_(go[r] + b3);
        const bool first = dir ? (t == lnv - 1) : (t == 0);
        const float cn = fv * (first ? 0.0f : cv[r]) + iv * gv;
        cv[r] = cn;
        hw[(size_t)(n0 + r) * H_DIM + j] = f2bf(ov * tanhf_(cn));
      }
    }
    *(f32x4*)&cT[(size_t)j * N_SEQ + n0] = cv;
  }
}

// ---------------- fused segment-mean pool (parity select) + linear + L2 normalize ----------------

__global__ __launch_bounds__(256) void k_poolfinal(const ush* __restrict__ h0f, const ush* __restrict__ h1f,
                                                   const ush* __restrict__ h0b,
                                                   const int* __restrict__ pinv, const int* __restrict__ lens,
                                                   const int* __restrict__ plen,
                                                   const float* __restrict__ W, const float* __restrict__ bl,
                                                   float* __restrict__ out) {
  const int b = blockIdx.x, tid = threadIdx.x;
  __shared__ float pv[512];
  __shared__ float pre[512];
  __shared__ float red[4];
  int start = 0;
  for (int i = 0; i < b; ++i) start += plen[i];
  const int cnt = plen[b];
  float s0 = 0.f, s1 = 0.f;
  for (int r = 0; r < cnt; ++r) {
    const int n = start + r;
    const size_t pr = (size_t)pinv[n];
    const int l = lens[n];
    // fwd last write at s=l-1: s even -> h1f, s odd -> h0f  => l odd -> h1f, l even -> h0f
    const ush* hf = (l & 1) ? h1f : h0f;
    s0 += bf2f(hf[pr * H_DIM + tid]);
    s1 += bf2f(h0b[pr * H_DIM + tid]);  // bwd always last-written at s=15 (odd) -> h0b
  }
  const float inv = 1.0f / (float)cnt;
  pv[tid] = s0 * inv;
  pv[tid + 256] = s1 * inv;
  __syncthreads();
#pragma unroll
  for (int half = 0; half < 2; ++half) {
    const int dd = tid + half * 256;
    const f32x4* wr = (const f32x4*)(W + (size_t)dd * 512);
    const f32x4* pvv = (const f32x4*)pv;
    float s = bl[dd];
#pragma unroll 4
    for (int k4 = 0; k4 < 128; ++k4) {
      f32x4 wv = wr[k4], xv = pvv[k4];
      s += wv[0] * xv[0] + wv[1] * xv[1] + wv[2] * xv[2] + wv[3] * xv[3];
    }
    pre[dd] = s;
  }
  __syncthreads();
  float ss = pre[tid] * pre[tid] + pre[tid + 256] * pre[tid + 256];
#pragma unroll
  for (int off = 32; off > 0; off >>= 1) ss += __shfl_down(ss, off, 64);
  if ((tid & 63) == 0) red[tid >> 6] = ss;
  __syncthreads();
  float tot = red[0] + red[1] + red[2] + red[3];
  float scale = 1.0f / fmaxf(sqrtf(tot), 1e-5f);
  out[b * 512 + tid] = pre[tid] * scale;
  out[b * 512 + 256 + tid] = pre[tid + 256] * scale;
}

// ---------------- launch ----------------

extern "C" void kernel_launch(void* const* d_in, const int* in_sizes, int n_in,
                              void* d_out, int out_size, void* d_ws, size_t ws_size,
                              hipStream_t stream) {
  const int* tok    = (const int*)d_in[0];
  const int* plen   = (const int*)d_in[1];
  const float* emb  = (const float*)d_in[2];
  const float* Wih_f = (const float*)d_in[3];
  const float* Whh_f = (const float*)d_in[4];
  const float* b_f   = (const float*)d_in[5];
  const float* Wih_b = (const float*)d_in[6];
  const float* Whh_b = (const float*)d_in[7];
  const float* b_b   = (const float*)d_in[8];
  const float* Wlin  = (const float*)d_in[9];
  const float* blin  = (const float*)d_in[10];
  float* out = (float*)d_out;

  char* ws = (char*)d_ws;
  size_t off = 0;
  auto alloc = [&](size_t bytes) {
    void* p = ws + off;
    off = (off + bytes + 255) & ~(size_t)255;
    return p;
  };
  ush* embbf   = (ush*)alloc((size_t)V_SIZE * E_DIM * 2);
  ush* wptf    = (ush*)alloc((size_t)1024 * K_DIM * 2);
  ush* wptb    = (ush*)alloc((size_t)1024 * K_DIM * 2);
  int* lens    = (int*)alloc((size_t)N_SEQ * 4);
  int* perm    = (int*)alloc((size_t)N_SEQ * 4);
  int* pinv    = (int*)alloc((size_t)N_SEQ * 4);
  int* plens   = (int*)alloc((size_t)N_SEQ * 4);
  int* tokperm = (int*)alloc((size_t)T_LEN * N_SEQ * 4);
  int* blockhist = (int*)alloc((size_t)NBLK_LENS * 17 * 4);
  int* base    = (int*)alloc((size_t)NBLK_LENS * 17 * 4);
  int* cnts    = (int*)alloc(16 * 4);
  ush* h0f     = (ush*)alloc((size_t)N_SEQ * H_DIM * 2);
  ush* h1f     = (ush*)alloc((size_t)N_SEQ * H_DIM * 2);
  ush* h0b     = (ush*)alloc((size_t)N_SEQ * H_DIM * 2);
  ush* h1b     = (ush*)alloc((size_t)N_SEQ * H_DIM * 2);
  float* cTf   = (float*)alloc((size_t)H_DIM * N_SEQ * 4);
  float* cTb   = (float*)alloc((size_t)H_DIM * N_SEQ * 4);

  hipMemsetAsync(h0f, 0, (size_t)N_SEQ * H_DIM * 2, stream);
  hipMemsetAsync(h1f, 0, (size_t)N_SEQ * H_DIM * 2, stream);
  hipMemsetAsync(h0b, 0, (size_t)N_SEQ * H_DIM * 2, stream);
  hipMemsetAsync(h1b, 0, (size_t)N_SEQ * H_DIM * 2, stream);

  k_lens<<<NBLK_LENS, 256, 0, stream>>>(tok, lens, blockhist);
  k_offsets<<<1, 64, 0, stream>>>(blockhist, base, cnts);
  k_scatter<<<NBLK_LENS, 256, 0, stream>>>(lens, base, perm, pinv, plens);
  k_tokperm<<<(T_LEN * N_SEQ) / 256, 256, 0, stream>>>(tok, perm, tokperm);
  k_embcvt<<<(V_SIZE * E_DIM) / 256, 256, 0, stream>>>(emb, embbf);
  k_wprep<<<(2 * 1024 * K_DIM) / 256, 256, 0, stream>>>(Wih_f, Whh_f, Wih_b, Whh_b, wptf, wptb);

  dim3 grid(512, 2);
  for (int s = 0; s < T_LEN; ++s) {
    const ush* hrf = (s & 1) ? h1f : h0f;
    ush* hwf       = (s & 1) ? h0f : h1f;
    const ush* hrb = (s & 1) ? h1b : h0b;
    ush* hwb       = (s & 1) ? h0b : h1b;
    k_step<<<grid, 512, 0, stream>>>(embbf, tokperm, plens, cnts, wptf, wptb,
                                     b_f, b_b, hrf, hwf, hrb, hwb, cTf, cTb, s);
  }
  k_poolfinal<<<B_SAMP, 256, 0, stream>>>(h0f, h1f, h0b, pinv, lens, plen, Wlin, blin, out);
}

// Round 17
// 935.720 us; speedup vs baseline: 3.4607x; 3.4607x over previous
//
#include <hip/hip_runtime.h>
#include <stdint.h>

#define N_SEQ 16384
#define T_LEN 16
#define E_DIM 256
#define H_DIM 256
#define K_DIM 512
#define B_SAMP 128
#define V_SIZE 10000
#define NBLK_LENS (N_SEQ / 256)

typedef __bf16 bf16x8 __attribute__((ext_vector_type(8)));
typedef float  f32x4  __attribute__((ext_vector_type(4)));
typedef unsigned short ush;

__device__ __forceinline__ ush f2bf(float x) {
  unsigned int u = __float_as_uint(x);
  u = (u + 0x7fffu + ((u >> 16) & 1u)) >> 16;
  return (ush)u;
}
__device__ __forceinline__ float bf2f(ush v) {
  return __uint_as_float(((unsigned int)v) << 16);
}
__device__ __forceinline__ float sigmoidf_(float x) {
  return 1.0f / (1.0f + __expf(-x));
}
__device__ __forceinline__ float tanhf_(float x) {
  float e = __expf(2.0f * x);
  return 1.0f - 2.0f / (e + 1.0f);
}
__device__ __forceinline__ void glds16(const void* g, const void* l) {
  __builtin_amdgcn_global_load_lds(
      (const __attribute__((address_space(1))) unsigned int*)g,
      (__attribute__((address_space(3))) unsigned int*)l, 16, 0, 0);
}

// ---------------- prep kernels ----------------

// lens + per-block histogram (no global atomics)
__global__ __launch_bounds__(256) void k_lens(const int* __restrict__ tok, int* __restrict__ lens,
                                              int* __restrict__ blockhist) {
  __shared__ int lh[17];
  if (threadIdx.x < 17) lh[threadIdx.x] = 0;
  __syncthreads();
  int n = blockIdx.x * 256 + threadIdx.x;
  const int* r = tok + n * T_LEN;
  int c = 0;
#pragma unroll
  for (int t = 0; t < T_LEN; ++t) c += (r[t] != 0);
  lens[n] = c;
  atomicAdd(&lh[c], 1);  // LDS atomic: cheap
  __syncthreads();
  if (threadIdx.x < 17) blockhist[blockIdx.x * 17 + threadIdx.x] = lh[threadIdx.x];
}

// descending-length bucket starts + per-block bases + cnts[t] = count(len > t)
__global__ void k_offsets(const int* __restrict__ blockhist, int* __restrict__ base,
                          int* __restrict__ cnts) {
  if (threadIdx.x == 0) {
    int tot[17];
    for (int l = 0; l <= 16; ++l) {
      int s = 0;
      for (int b = 0; b < NBLK_LENS; ++b) s += blockhist[b * 17 + l];
      tot[l] = s;
    }
    int start[17];
    int off = 0;
    for (int l = 16; l >= 0; --l) { start[l] = off; off += tot[l]; }
    for (int l = 0; l <= 16; ++l) {
      int run = start[l];
      for (int b = 0; b < NBLK_LENS; ++b) { base[b * 17 + l] = run; run += blockhist[b * 17 + l]; }
    }
    for (int t = 0; t < 16; ++t) {
      int c = 0;
      for (int l = t + 1; l <= 16; ++l) c += tot[l];
      cnts[t] = c;
    }
  }
}

// rank via LDS atomics + per-block base (no global atomic contention)
__global__ __launch_bounds__(256) void k_scatter(const int* __restrict__ lens, const int* __restrict__ base,
                                                 int* __restrict__ perm, int* __restrict__ pinv,
                                                 int* __restrict__ plens) {
  __shared__ int lh[17];
  if (threadIdx.x < 17) lh[threadIdx.x] = 0;
  __syncthreads();
  int n = blockIdx.x * 256 + threadIdx.x;
  int l = lens[n];
  int lr = atomicAdd(&lh[l], 1);
  int pos = base[blockIdx.x * 17 + l] + lr;
  perm[pos] = n;
  pinv[n] = pos;
  plens[pos] = l;
}

// gather form: coalesced writes; tok (1 MB) is L2-resident
__global__ __launch_bounds__(256) void k_tokperm(const int* __restrict__ tok, const int* __restrict__ perm,
                                                 int* __restrict__ tokperm) {
  int id = blockIdx.x * 256 + threadIdx.x;  // < T_LEN * N_SEQ
  int t = id >> 14;                          // N_SEQ = 2^14
  int pos = id & (N_SEQ - 1);
  tokperm[id] = tok[perm[pos] * T_LEN + t];
}

__global__ __launch_bounds__(256) void k_embcvt(const float* __restrict__ emb, ush* __restrict__ out) {
  int i = blockIdx.x * 256 + threadIdx.x;
  out[i] = f2bf(emb[i]);
}

// Permuted weights: wpt[p][k], p = nb*256 + wc*64 + q*16 + jj  <->
// gate-row r = q*256 + (nb*64 + wc*16 + jj);  k<256 -> W_ih[r][k], else W_hh[r][k-256].
__global__ __launch_bounds__(256) void k_wprep(const float* __restrict__ Wih_f, const float* __restrict__ Whh_f,
                                               const float* __restrict__ Wih_b, const float* __restrict__ Whh_b,
                                               ush* __restrict__ wpt_f, ush* __restrict__ wpt_b) {
  int id = blockIdx.x * 256 + threadIdx.x;  // < 2*1024*512
  int dir = id >> 19;
  int rem = id & ((1 << 19) - 1);
  int p = rem >> 9;
  int k = rem & 511;
  int nb = p >> 8, wc = (p >> 6) & 3, q = (p >> 4) & 3, jj = p & 15;
  int r = q * 256 + nb * 64 + wc * 16 + jj;
  const float* Wih = dir ? Wih_b : Wih_f;
  const float* Whh = dir ? Whh_b : Whh_f;
  float v = (k < 256) ? Wih[r * 256 + k] : Whh[r * 256 + (k - 256)];
  ush* o = dir ? wpt_b : wpt_f;
  o[p * 512 + k] = f2bf(v);
}

// ---------------- LSTM step: K=512 fused GEMM + cell update ----------------
// R15 core (measured best): grid(512,2), 512 thr / 8 waves (2x4), tile 128 rows x
// 256 pcols, K=512 in 8 chunks of 64; XOR-swizzled LDS (conflict-free); glds16
// staging; 2 barriers/chunk; parity pooling (no copies); first-active-step c init.
// R17 micro-opts: cT[j][n] f32 transposed cell state (f32x4 full-line access),
// c/bias/lens prefetched before GEMM, group-graduation store skip.
// launch_bounds (512,4): VGPR cap 128 — (512,6) caused scratch spill (R16, 4x regress).

__global__ __launch_bounds__(512, 4)
void k_step(const ush* __restrict__ embbf, const int* __restrict__ tokperm,
            const int* __restrict__ plens, const int* __restrict__ cnts,
            const ush* __restrict__ wpt_f, const ush* __restrict__ wpt_b,
            const float* __restrict__ bias_f, const float* __restrict__ bias_b,
            const ush* __restrict__ hr_f, ush* __restrict__ hw_f,
            const ush* __restrict__ hr_b, ush* __restrict__ hw_b,
            float* __restrict__ cT_f, float* __restrict__ cT_b,
            int s) {
  const int dir = blockIdx.y;
  const int t = dir ? (15 - s) : s;
  const int cnt = cnts[t];
  const int mblk = blockIdx.x >> 2;
  const int m0 = mblk * 128;
  if (m0 >= cnt) return;

  const int nblk = blockIdx.x & 3;
  const ush* wpt = dir ? wpt_b : wpt_f;
  const float* bias = dir ? bias_b : bias_f;
  const ush* hr = dir ? hr_b : hr_f;
  ush* hw = dir ? hw_b : hw_f;
  float* cT = dir ? cT_b : cT_f;

  __shared__ __align__(128) unsigned char ldsA[128 * 128];  // 16 KB
  __shared__ __align__(128) unsigned char ldsB[256 * 128];  // 32 KB

  const int tid = threadIdx.x;
  const int lane = tid & 63;
  const int w = tid >> 6;
  const int wr = w >> 2;
  const int wc = w & 3;
  const int frow = lane & 15;
  const int fkq = lane >> 4;  // 0..3

  // ---- epilogue prefetch: bias, lens, c (independent of the GEMM; hides latency) ----
  const int j = nblk * 64 + wc * 16 + frow;
  const float b0 = bias[j], b1 = bias[256 + j], b2 = bias[512 + j], b3 = bias[768 + j];
  int4 l4[4];
  f32x4 cv4[4];
#pragma unroll
  for (int fr = 0; fr < 4; ++fr) {
    const int n0 = m0 + wr * 64 + fr * 16 + fkq * 4;
    l4[fr] = *(const int4*)&plens[n0];
    cv4[fr] = *(const f32x4*)&cT[(size_t)j * N_SEQ + n0];
  }

  // ---- staging address precompute (element offsets, fixed per thread) ----
  const int l8 = lane >> 3;        // sub-row within 8-row group
  const int l7 = lane & 7;         // chunk slot in LDS
  const int arow0 = 16 * w + l8;
  const int arow1 = arow0 + 8;
  const int ach0 = l7 ^ (arow0 & 7);
  const int ach1 = l7 ^ (arow1 & 7);
  const unsigned aoffE0 = (unsigned)tokperm[t * N_SEQ + m0 + arow0] * E_DIM + ach0 * 8;
  const unsigned aoffE1 = (unsigned)tokperm[t * N_SEQ + m0 + arow1] * E_DIM + ach1 * 8;
  const unsigned aoffH0 = (unsigned)(m0 + arow0) * H_DIM + ach0 * 8;
  const unsigned aoffH1 = (unsigned)(m0 + arow1) * H_DIM + ach1 * 8;
  unsigned boff[4];
#pragma unroll
  for (int jj = 0; jj < 4; ++jj) {
    const int brow = 32 * w + 8 * jj + l8;
    const int bch = l7 ^ (brow & 7);
    boff[jj] = (unsigned)(nblk * 256 + brow) * K_DIM + bch * 8;
  }

  f32x4 acc[4][4] = {};

  for (int kt = 0; kt < 8; ++kt) {
    const int k0 = kt * 64;
    if (kt < 4) {
      glds16(embbf + aoffE0 + k0, &ldsA[(16 * w) * 128]);
      glds16(embbf + aoffE1 + k0, &ldsA[(16 * w + 8) * 128]);
    } else {
      glds16(hr + aoffH0 + (k0 - E_DIM), &ldsA[(16 * w) * 128]);
      glds16(hr + aoffH1 + (k0 - E_DIM), &ldsA[(16 * w + 8) * 128]);
    }
#pragma unroll
    for (int jj = 0; jj < 4; ++jj)
      glds16(wpt + boff[jj] + k0, &ldsB[(32 * w + 8 * jj) * 128]);
    __syncthreads();
#pragma unroll
    for (int ksub = 0; ksub < 2; ++ksub) {
      bf16x8 av[4], bv[4];
#pragma unroll
      for (int fr = 0; fr < 4; ++fr) {
        const int row = wr * 64 + fr * 16 + frow;
        const int ch = (ksub * 4 + fkq) ^ (row & 7);
        av[fr] = *(const bf16x8*)&ldsA[row * 128 + ch * 16];
      }
#pragma unroll
      for (int fc = 0; fc < 4; ++fc) {
        const int row = wc * 64 + fc * 16 + frow;
        const int ch = (ksub * 4 + fkq) ^ (row & 7);
        bv[fc] = *(const bf16x8*)&ldsB[row * 128 + ch * 16];
      }
#pragma unroll
      for (int fr = 0; fr < 4; ++fr)
#pragma unroll
        for (int fc = 0; fc < 4; ++fc)
          acc[fr][fc] = __builtin_amdgcn_mfma_f32_16x16x32_bf16(av[fr], bv[fc], acc[fr][fc], 0, 0, 0);
    }
    __syncthreads();
  }

  // ---- fused LSTM cell update: fc = gate (i,f,g,o) for hidden unit j; no copies ----
#pragma unroll
  for (int fr = 0; fr < 4; ++fr) {
    const int n0 = m0 + wr * 64 + fr * 16 + fkq * 4;
    const int4 ln = l4[fr];
    const int lmax = max(max(ln.x, ln.y), max(ln.z, ln.w));
    if (t >= lmax) continue;  // whole row-group graduated: no writes
    f32x4 cv = cv4[fr];
    const f32x4 gi = acc[fr][0], gf = acc[fr][1], gg = acc[fr][2], go = acc[fr][3];
#pragma unroll
    for (int r = 0; r < 4; ++r) {
      const int lnv = (r == 0) ? ln.x : (r == 1) ? ln.y : (r == 2) ? ln.z : ln.w;
      if (t < lnv) {
        const float iv = sigmoidf_(gi[r] + b0);
        const float fv = sigmoidf_(gf[r] + b1);
        const float gv = tanhf_(gg[r] + b2);
        const float ov = sigmoidf_(go[r] + b3);
        const bool first = dir ? (t == lnv - 1) : (t == 0);
        const float cn = fv * (first ? 0.0f : cv[r]) + iv * gv;
        cv[r] = cn;
        hw[(size_t)(n0 + r) * H_DIM + j] = f2bf(ov * tanhf_(cn));
      }
    }
    *(f32x4*)&cT[(size_t)j * N_SEQ + n0] = cv;
  }
}

// ---------------- fused segment-mean pool (parity select) + linear + L2 normalize ----------------

__global__ __launch_bounds__(256) void k_poolfinal(const ush* __restrict__ h0f, const ush* __restrict__ h1f,
                                                   const ush* __restrict__ h0b,
                                                   const int* __restrict__ pinv, const int* __restrict__ lens,
                                                   const int* __restrict__ plen,
                                                   const float* __restrict__ W, const float* __restrict__ bl,
                                                   float* __restrict__ out) {
  const int b = blockIdx.x, tid = threadIdx.x;
  __shared__ float pv[512];
  __shared__ float pre[512];
  __shared__ float red[4];
  int start = 0;
  for (int i = 0; i < b; ++i) start += plen[i];
  const int cnt = plen[b];
  float s0 = 0.f, s1 = 0.f;
  for (int r = 0; r < cnt; ++r) {
    const int n = start + r;
    const size_t pr = (size_t)pinv[n];
    const int l = lens[n];
    // fwd last write at s=l-1: s even -> h1f, s odd -> h0f  => l odd -> h1f, l even -> h0f
    const ush* hf = (l & 1) ? h1f : h0f;
    s0 += bf2f(hf[pr * H_DIM + tid]);
    s1 += bf2f(h0b[pr * H_DIM + tid]);  // bwd always last-written at s=15 (odd) -> h0b
  }
  const float inv = 1.0f / (float)cnt;
  pv[tid] = s0 * inv;
  pv[tid + 256] = s1 * inv;
  __syncthreads();
#pragma unroll
  for (int half = 0; half < 2; ++half) {
    const int dd = tid + half * 256;
    const f32x4* wr = (const f32x4*)(W + (size_t)dd * 512);
    const f32x4* pvv = (const f32x4*)pv;
    float s = bl[dd];
#pragma unroll 4
    for (int k4 = 0; k4 < 128; ++k4) {
      f32x4 wv = wr[k4], xv = pvv[k4];
      s += wv[0] * xv[0] + wv[1] * xv[1] + wv[2] * xv[2] + wv[3] * xv[3];
    }
    pre[dd] = s;
  }
  __syncthreads();
  float ss = pre[tid] * pre[tid] + pre[tid + 256] * pre[tid + 256];
#pragma unroll
  for (int off = 32; off > 0; off >>= 1) ss += __shfl_down(ss, off, 64);
  if ((tid & 63) == 0) red[tid >> 6] = ss;
  __syncthreads();
  float tot = red[0] + red[1] + red[2] + red[3];
  float scale = 1.0f / fmaxf(sqrtf(tot), 1e-5f);
  out[b * 512 + tid] = pre[tid] * scale;
  out[b * 512 + 256 + tid] = pre[tid + 256] * scale;
}

// ---------------- launch ----------------

extern "C" void kernel_launch(void* const* d_in, const int* in_sizes, int n_in,
                              void* d_out, int out_size, void* d_ws, size_t ws_size,
                              hipStream_t stream) {
  const int* tok    = (const int*)d_in[0];
  const int* plen   = (const int*)d_in[1];
  const float* emb  = (const float*)d_in[2];
  const float* Wih_f = (const float*)d_in[3];
  const float* Whh_f = (const float*)d_in[4];
  const float* b_f   = (const float*)d_in[5];
  const float* Wih_b = (const float*)d_in[6];
  const float* Whh_b = (const float*)d_in[7];
  const float* b_b   = (const float*)d_in[8];
  const float* Wlin  = (const float*)d_in[9];
  const float* blin  = (const float*)d_in[10];
  float* out = (float*)d_out;

  char* ws = (char*)d_ws;
  size_t off = 0;
  auto alloc = [&](size_t bytes) {
    void* p = ws + off;
    off = (off + bytes + 255) & ~(size_t)255;
    return p;
  };
  ush* embbf   = (ush*)alloc((size_t)V_SIZE * E_DIM * 2);
  ush* wptf    = (ush*)alloc((size_t)1024 * K_DIM * 2);
  ush* wptb    = (ush*)alloc((size_t)1024 * K_DIM * 2);
  int* lens    = (int*)alloc((size_t)N_SEQ * 4);
  int* perm    = (int*)alloc((size_t)N_SEQ * 4);
  int* pinv    = (int*)alloc((size_t)N_SEQ * 4);
  int* plens   = (int*)alloc((size_t)N_SEQ * 4);
  int* tokperm = (int*)alloc((size_t)T_LEN * N_SEQ * 4);
  int* blockhist = (int*)alloc((size_t)NBLK_LENS * 17 * 4);
  int* base    = (int*)alloc((size_t)NBLK_LENS * 17 * 4);
  int* cnts    = (int*)alloc(16 * 4);
  ush* h0f     = (ush*)alloc((size_t)N_SEQ * H_DIM * 2);
  ush* h1f     = (ush*)alloc((size_t)N_SEQ * H_DIM * 2);
  ush* h0b     = (ush*)alloc((size_t)N_SEQ * H_DIM * 2);
  ush* h1b     = (ush*)alloc((size_t)N_SEQ * H_DIM * 2);
  float* cTf   = (float*)alloc((size_t)H_DIM * N_SEQ * 4);
  float* cTb   = (float*)alloc((size_t)H_DIM * N_SEQ * 4);

  hipMemsetAsync(h0f, 0, (size_t)N_SEQ * H_DIM * 2, stream);
  hipMemsetAsync(h1f, 0, (size_t)N_SEQ * H_DIM * 2, stream);
  hipMemsetAsync(h0b, 0, (size_t)N_SEQ * H_DIM * 2, stream);
  hipMemsetAsync(h1b, 0, (size_t)N_SEQ * H_DIM * 2, stream);

  k_lens<<<NBLK_LENS, 256, 0, stream>>>(tok, lens, blockhist);
  k_offsets<<<1, 64, 0, stream>>>(blockhist, base, cnts);
  k_scatter<<<NBLK_LENS, 256, 0, stream>>>(lens, base, perm, pinv, plens);
  k_tokperm<<<(T_LEN * N_SEQ) / 256, 256, 0, stream>>>(tok, perm, tokperm);
  k_embcvt<<<(V_SIZE * E_DIM) / 256, 256, 0, stream>>>(emb, embbf);
  k_wprep<<<(2 * 1024 * K_DIM) / 256, 256, 0, stream>>>(Wih_f, Whh_f, Wih_b, Whh_b, wptf, wptb);

  dim3 grid(512, 2);
  for (int s = 0; s < T_LEN; ++s) {
    const ush* hrf = (s & 1) ? h1f : h0f;
    ush* hwf       = (s & 1) ? h0f : h1f;
    const ush* hrb = (s & 1) ? h1b : h0b;
    ush* hwb       = (s & 1) ? h0b : h1b;
    k_step<<<grid, 512, 0, stream>>>(embbf, tokperm, plens, cnts, wptf, wptb,
                                     b_f, b_b, hrf, hwf, hrb, hwb, cTf, cTb, s);
  }
  k_poolfinal<<<B_SAMP, 256, 0, stream>>>(h0f, h1f, h0b, pinv, lens, plen, Wlin, blin, out);
}

// Round 19
// 817.131 us; speedup vs baseline: 3.9629x; 1.1451x over previous
//
#include <hip/hip_runtime.h>
#include <stdint.h>

#define N_SEQ 16384
#define T_LEN 16
#define E_DIM 256
#define H_DIM 256
#define K_DIM 512
#define B_SAMP 128
#define V_SIZE 10000
#define NBLK_LENS (N_SEQ / 256)

typedef __bf16 bf16x8 __attribute__((ext_vector_type(8)));
typedef float  f32x4  __attribute__((ext_vector_type(4)));
typedef unsigned short ush;

__device__ __forceinline__ ush f2bf(float x) {
  unsigned int u = __float_as_uint(x);
  u = (u + 0x7fffu + ((u >> 16) & 1u)) >> 16;
  return (ush)u;
}
__device__ __forceinline__ float bf2f(ush v) {
  return __uint_as_float(((unsigned int)v) << 16);
}
__device__ __forceinline__ float sigmoidf_(float x) {
  return 1.0f / (1.0f + __expf(-x));
}
__device__ __forceinline__ float tanhf_(float x) {
  float e = __expf(2.0f * x);
  return 1.0f - 2.0f / (e + 1.0f);
}
__device__ __forceinline__ void glds16(const void* g, const void* l) {
  __builtin_amdgcn_global_load_lds(
      (const __attribute__((address_space(1))) unsigned int*)g,
      (__attribute__((address_space(3))) unsigned int*)l, 16, 0, 0);
}

// ---------------- prep kernels ----------------

// lens + per-block histogram (no global atomics)
__global__ __launch_bounds__(256) void k_lens(const int* __restrict__ tok, int* __restrict__ lens,
                                              int* __restrict__ blockhist) {
  __shared__ int lh[17];
  if (threadIdx.x < 17) lh[threadIdx.x] = 0;
  __syncthreads();
  int n = blockIdx.x * 256 + threadIdx.x;
  const int* r = tok + n * T_LEN;
  int c = 0;
#pragma unroll
  for (int t = 0; t < T_LEN; ++t) c += (r[t] != 0);
  lens[n] = c;
  atomicAdd(&lh[c], 1);  // LDS atomic: cheap
  __syncthreads();
  if (threadIdx.x < 17) blockhist[blockIdx.x * 17 + threadIdx.x] = lh[threadIdx.x];
}

// descending-length bucket starts + per-block bases + cnts[t] = count(len > t)
__global__ void k_offsets(const int* __restrict__ blockhist, int* __restrict__ base,
                          int* __restrict__ cnts) {
  if (threadIdx.x == 0) {
    int tot[17];
    for (int l = 0; l <= 16; ++l) {
      int s = 0;
      for (int b = 0; b < NBLK_LENS; ++b) s += blockhist[b * 17 + l];
      tot[l] = s;
    }
    int start[17];
    int off = 0;
    for (int l = 16; l >= 0; --l) { start[l] = off; off += tot[l]; }
    for (int l = 0; l <= 16; ++l) {
      int run = start[l];
      for (int b = 0; b < NBLK_LENS; ++b) { base[b * 17 + l] = run; run += blockhist[b * 17 + l]; }
    }
    for (int t = 0; t < 16; ++t) {
      int c = 0;
      for (int l = t + 1; l <= 16; ++l) c += tot[l];
      cnts[t] = c;
    }
  }
}

// rank via LDS atomics + per-block base (no global atomic contention)
__global__ __launch_bounds__(256) void k_scatter(const int* __restrict__ lens, const int* __restrict__ base,
                                                 int* __restrict__ perm, int* __restrict__ pinv,
                                                 int* __restrict__ plens) {
  __shared__ int lh[17];
  if (threadIdx.x < 17) lh[threadIdx.x] = 0;
  __syncthreads();
  int n = blockIdx.x * 256 + threadIdx.x;
  int l = lens[n];
  int lr = atomicAdd(&lh[l], 1);
  int pos = base[blockIdx.x * 17 + l] + lr;
  perm[pos] = n;
  pinv[n] = pos;
  plens[pos] = l;
}

// gather form: coalesced writes; tok (1 MB) is L2-resident
__global__ __launch_bounds__(256) void k_tokperm(const int* __restrict__ tok, const int* __restrict__ perm,
                                                 int* __restrict__ tokperm) {
  int id = blockIdx.x * 256 + threadIdx.x;  // < T_LEN * N_SEQ
  int t = id >> 14;                          // N_SEQ = 2^14
  int pos = id & (N_SEQ - 1);
  tokperm[id] = tok[perm[pos] * T_LEN + t];
}

__global__ __launch_bounds__(256) void k_embcvt(const float* __restrict__ emb, ush* __restrict__ out) {
  int i = blockIdx.x * 256 + threadIdx.x;
  out[i] = f2bf(emb[i]);
}

// Permuted weights: wpt[p][k], p = nb*256 + wc*64 + q*16 + jj  <->
// gate-row r = q*256 + (nb*64 + wc*16 + jj);  k<256 -> W_ih[r][k], else W_hh[r][k-256].
__global__ __launch_bounds__(256) void k_wprep(const float* __restrict__ Wih_f, const float* __restrict__ Whh_f,
                                               const float* __restrict__ Wih_b, const float* __restrict__ Whh_b,
                                               ush* __restrict__ wpt_f, ush* __restrict__ wpt_b) {
  int id = blockIdx.x * 256 + threadIdx.x;  // < 2*1024*512
  int dir = id >> 19;
  int rem = id & ((1 << 19) - 1);
  int p = rem >> 9;
  int k = rem & 511;
  int nb = p >> 8, wc = (p >> 6) & 3, q = (p >> 4) & 3, jj = p & 15;
  int r = q * 256 + nb * 64 + wc * 16 + jj;
  const float* Wih = dir ? Wih_b : Wih_f;
  const float* Whh = dir ? Whh_b : Whh_f;
  float v = (k < 256) ? Wih[r * 256 + k] : Whh[r * 256 + (k - 256)];
  ush* o = dir ? wpt_b : wpt_f;
  o[p * 512 + k] = f2bf(v);
}

// ---------------- LSTM step: K=512 fused GEMM + cell update (R15 core, measured best) ----------------
// grid(512,2): mblk = bid.x>>2, nblk = bid.x&3, dir = bid.y. Length-sorted rows;
// active prefix cnts[t] = count(len>t); blocks past it exit. 512 thr / 8 waves (2x4),
// tile 128 rows x 256 pcols, K=512 in 8 chunks of 64; XOR-swizzled LDS (measured
// conflict-free); glds16 staging; 2 barriers/chunk. Parity pooling: NO graduation
// copies; first-active-step c init (no c memsets). VGPR 64 — do not add pre-GEMM
// prefetch (R17: occupancy drop) or min-waves 6 (R16: scratch spill, 4x regress).

__global__ __launch_bounds__(512, 4)
void k_step(const ush* __restrict__ embbf, const int* __restrict__ tokperm,
            const int* __restrict__ plens, const int* __restrict__ cnts,
            const ush* __restrict__ wpt_f, const ush* __restrict__ wpt_b,
            const float* __restrict__ bias_f, const float* __restrict__ bias_b,
            const ush* __restrict__ hr_f, ush* __restrict__ hw_f,
            const ush* __restrict__ hr_b, ush* __restrict__ hw_b,
            float* __restrict__ c_f, float* __restrict__ c_b,
            int s) {
  const int dir = blockIdx.y;
  const int t = dir ? (15 - s) : s;
  const int cnt = cnts[t];
  const int mblk = blockIdx.x >> 2;
  const int m0 = mblk * 128;
  if (m0 >= cnt) return;

  const int nblk = blockIdx.x & 3;
  const ush* wpt = dir ? wpt_b : wpt_f;
  const float* bias = dir ? bias_b : bias_f;
  const ush* hr = dir ? hr_b : hr_f;
  ush* hw = dir ? hw_b : hw_f;
  float* cc = dir ? c_b : c_f;

  __shared__ __align__(128) unsigned char ldsA[128 * 128];  // 16 KB
  __shared__ __align__(128) unsigned char ldsB[256 * 128];  // 32 KB

  const int tid = threadIdx.x;
  const int lane = tid & 63;
  const int w = tid >> 6;
  const int wr = w >> 2;
  const int wc = w & 3;

  // ---- staging address precompute (element offsets, fixed per thread) ----
  const int l8 = lane >> 3;        // sub-row within 8-row group
  const int l7 = lane & 7;         // chunk slot in LDS
  const int arow0 = 16 * w + l8;
  const int arow1 = arow0 + 8;
  const int ach0 = l7 ^ (arow0 & 7);
  const int ach1 = l7 ^ (arow1 & 7);
  const unsigned aoffE0 = (unsigned)tokperm[t * N_SEQ + m0 + arow0] * E_DIM + ach0 * 8;
  const unsigned aoffE1 = (unsigned)tokperm[t * N_SEQ + m0 + arow1] * E_DIM + ach1 * 8;
  const unsigned aoffH0 = (unsigned)(m0 + arow0) * H_DIM + ach0 * 8;
  const unsigned aoffH1 = (unsigned)(m0 + arow1) * H_DIM + ach1 * 8;
  unsigned boff[4];
#pragma unroll
  for (int jj = 0; jj < 4; ++jj) {
    const int brow = 32 * w + 8 * jj + l8;
    const int bch = l7 ^ (brow & 7);
    boff[jj] = (unsigned)(nblk * 256 + brow) * K_DIM + bch * 8;
  }

  f32x4 acc[4][4] = {};
  const int frow = lane & 15;
  const int fkq = lane >> 4;  // 0..3

  for (int kt = 0; kt < 8; ++kt) {
    const int k0 = kt * 64;
    if (kt < 4) {
      glds16(embbf + aoffE0 + k0, &ldsA[(16 * w) * 128]);
      glds16(embbf + aoffE1 + k0, &ldsA[(16 * w + 8) * 128]);
    } else {
      glds16(hr + aoffH0 + (k0 - E_DIM), &ldsA[(16 * w) * 128]);
      glds16(hr + aoffH1 + (k0 - E_DIM), &ldsA[(16 * w + 8) * 128]);
    }
#pragma unroll
    for (int jj = 0; jj < 4; ++jj)
      glds16(wpt + boff[jj] + k0, &ldsB[(32 * w + 8 * jj) * 128]);
    __syncthreads();
#pragma unroll
    for (int ksub = 0; ksub < 2; ++ksub) {
      bf16x8 av[4], bv[4];
#pragma unroll
      for (int fr = 0; fr < 4; ++fr) {
        const int row = wr * 64 + fr * 16 + frow;
        const int ch = (ksub * 4 + fkq) ^ (row & 7);
        av[fr] = *(const bf16x8*)&ldsA[row * 128 + ch * 16];
      }
#pragma unroll
      for (int fc = 0; fc < 4; ++fc) {
        const int row = wc * 64 + fc * 16 + frow;
        const int ch = (ksub * 4 + fkq) ^ (row & 7);
        bv[fc] = *(const bf16x8*)&ldsB[row * 128 + ch * 16];
      }
#pragma unroll
      for (int fr = 0; fr < 4; ++fr)
#pragma unroll
        for (int fc = 0; fc < 4; ++fc)
          acc[fr][fc] = __builtin_amdgcn_mfma_f32_16x16x32_bf16(av[fr], bv[fc], acc[fr][fc], 0, 0, 0);
    }
    __syncthreads();
  }

  // ---- fused LSTM cell update: fc = gate (i,f,g,o) for hidden unit j; no copies ----
  const int j = nblk * 64 + wc * 16 + frow;
  const float b0 = bias[j], b1 = bias[256 + j], b2 = bias[512 + j], b3 = bias[768 + j];
#pragma unroll
  for (int fr = 0; fr < 4; ++fr) {
    const int n0 = m0 + wr * 64 + fr * 16 + fkq * 4;
    const int4 l4 = *(const int4*)&plens[n0];
    const f32x4 gi = acc[fr][0], gf = acc[fr][1], gg = acc[fr][2], go = acc[fr][3];
#pragma unroll
    for (int r = 0; r < 4; ++r) {
      const int lnv = (r == 0) ? l4.x : (r == 1) ? l4.y : (r == 2) ? l4.z : l4.w;
      if (t < lnv) {
        const size_t idx = (size_t)(n0 + r) * H_DIM + j;
        const float iv = sigmoidf_(gi[r] + b0);
        const float fv = sigmoidf_(gf[r] + b1);
        const float gv = tanhf_(gg[r] + b2);
        const float ov = sigmoidf_(go[r] + b3);
        const bool first = dir ? (t == lnv - 1) : (t == 0);
        const float cn = fv * (first ? 0.0f : cc[idx]) + iv * gv;
        cc[idx] = cn;
        hw[idx] = f2bf(ov * tanhf_(cn));
      }
    }
  }
}

// ---------------- segment-mean pool with per-row parity buffer select ----------------

__global__ __launch_bounds__(256) void k_pool(const ush* __restrict__ h0f, const ush* __restrict__ h1f,
                                              const ush* __restrict__ h0b,
                                              const int* __restrict__ pinv, const int* __restrict__ lens,
                                              const int* __restrict__ plen,
                                              float* __restrict__ pooled) {
  const int b = blockIdx.x, tid = threadIdx.x;
  int start = 0;
  for (int i = 0; i < b; ++i) start += plen[i];
  const int cnt = plen[b];
  float s0 = 0.f, s1 = 0.f;
  for (int r = 0; r < cnt; ++r) {
    const int n = start + r;
    const size_t pr = (size_t)pinv[n];
    const int l = lens[n];
    // fwd last write at s=l-1: s even -> h1f, s odd -> h0f  => l odd -> h1f, l even -> h0f
    const ush* hf = (l & 1) ? h1f : h0f;
    s0 += bf2f(hf[pr * H_DIM + tid]);
    s1 += bf2f(h0b[pr * H_DIM + tid]);  // bwd always last-written at s=15 (odd) -> h0b
  }
  float inv = 1.0f / (float)cnt;
  pooled[b * 512 + tid] = s0 * inv;
  pooled[b * 512 + H_DIM + tid] = s1 * inv;
}

// ---------------- tiny linear (128x512x512) + L2 normalize, f32 ----------------

__global__ __launch_bounds__(256) void k_final(const float* __restrict__ pooled,
                                               const float* __restrict__ W,
                                               const float* __restrict__ bl,
                                               float* __restrict__ out) {
  const int b = blockIdx.x, tid = threadIdx.x;
  __shared__ float pv[512];
  __shared__ float pre[512];
  __shared__ float red[4];
  pv[tid] = pooled[b * 512 + tid];
  pv[tid + 256] = pooled[b * 512 + 256 + tid];
  __syncthreads();
#pragma unroll
  for (int half = 0; half < 2; ++half) {
    const int dd = tid + half * 256;
    const f32x4* wr = (const f32x4*)(W + (size_t)dd * 512);
    const f32x4* pvv = (const f32x4*)pv;
    float s = bl[dd];
#pragma unroll 4
    for (int k4 = 0; k4 < 128; ++k4) {
      f32x4 wv = wr[k4], xv = pvv[k4];
      s += wv[0] * xv[0] + wv[1] * xv[1] + wv[2] * xv[2] + wv[3] * xv[3];
    }
    pre[dd] = s;
  }
  __syncthreads();
  float ss = pre[tid] * pre[tid] + pre[tid + 256] * pre[tid + 256];
#pragma unroll
  for (int off = 32; off > 0; off >>= 1) ss += __shfl_down(ss, off, 64);
  if ((tid & 63) == 0) red[tid >> 6] = ss;
  __syncthreads();
  float tot = red[0] + red[1] + red[2] + red[3];
  float scale = 1.0f / fmaxf(sqrtf(tot), 1e-5f);
  out[b * 512 + tid] = pre[tid] * scale;
  out[b * 512 + 256 + tid] = pre[tid + 256] * scale;
}

// ---------------- launch ----------------

extern "C" void kernel_launch(void* const* d_in, const int* in_sizes, int n_in,
                              void* d_out, int out_size, void* d_ws, size_t ws_size,
                              hipStream_t stream) {
  const int* tok    = (const int*)d_in[0];
  const int* plen   = (const int*)d_in[1];
  const float* emb  = (const float*)d_in[2];
  const float* Wih_f = (const float*)d_in[3];
  const float* Whh_f = (const float*)d_in[4];
  const float* b_f   = (const float*)d_in[5];
  const float* Wih_b = (const float*)d_in[6];
  const float* Whh_b = (const float*)d_in[7];
  const float* b_b   = (const float*)d_in[8];
  const float* Wlin  = (const float*)d_in[9];
  const float* blin  = (const float*)d_in[10];
  float* out = (float*)d_out;

  char* ws = (char*)d_ws;
  size_t off = 0;
  auto alloc = [&](size_t bytes) {
    void* p = ws + off;
    off = (off + bytes + 255) & ~(size_t)255;
    return p;
  };
  ush* embbf   = (ush*)alloc((size_t)V_SIZE * E_DIM * 2);
  ush* wptf    = (ush*)alloc((size_t)1024 * K_DIM * 2);
  ush* wptb    = (ush*)alloc((size_t)1024 * K_DIM * 2);
  int* lens    = (int*)alloc((size_t)N_SEQ * 4);
  int* perm    = (int*)alloc((size_t)N_SEQ * 4);
  int* pinv    = (int*)alloc((size_t)N_SEQ * 4);
  int* plens   = (int*)alloc((size_t)N_SEQ * 4);
  int* tokperm = (int*)alloc((size_t)T_LEN * N_SEQ * 4);
  int* blockhist = (int*)alloc((size_t)NBLK_LENS * 17 * 4);
  int* base    = (int*)alloc((size_t)NBLK_LENS * 17 * 4);
  int* cnts    = (int*)alloc(16 * 4);
  ush* h0f     = (ush*)alloc((size_t)N_SEQ * H_DIM * 2);
  ush* h1f     = (ush*)alloc((size_t)N_SEQ * H_DIM * 2);
  ush* h0b     = (ush*)alloc((size_t)N_SEQ * H_DIM * 2);
  ush* h1b     = (ush*)alloc((size_t)N_SEQ * H_DIM * 2);
  float* cf    = (float*)alloc((size_t)N_SEQ * H_DIM * 4);
  float* cb    = (float*)alloc((size_t)N_SEQ * H_DIM * 4);
  float* pooled = (float*)alloc((size_t)B_SAMP * 512 * 4);

  hipMemsetAsync(h0f, 0, (size_t)N_SEQ * H_DIM * 2, stream);
  hipMemsetAsync(h1f, 0, (size_t)N_SEQ * H_DIM * 2, stream);
  hipMemsetAsync(h0b, 0, (size_t)N_SEQ * H_DIM * 2, stream);
  hipMemsetAsync(h1b, 0, (size_t)N_SEQ * H_DIM * 2, stream);

  k_lens<<<NBLK_LENS, 256, 0, stream>>>(tok, lens, blockhist);
  k_offsets<<<1, 64, 0, stream>>>(blockhist, base, cnts);
  k_scatter<<<NBLK_LENS, 256, 0, stream>>>(lens, base, perm, pinv, plens);
  k_tokperm<<<(T_LEN * N_SEQ) / 256, 256, 0, stream>>>(tok, perm, tokperm);
  k_embcvt<<<(V_SIZE * E_DIM) / 256, 256, 0, stream>>>(emb, embbf);
  k_wprep<<<(2 * 1024 * K_DIM) / 256, 256, 0, stream>>>(Wih_f, Whh_f, Wih_b, Whh_b, wptf, wptb);

  dim3 grid(512, 2);
  for (int s = 0; s < T_LEN; ++s) {
    const ush* hrf = (s & 1) ? h1f : h0f;
    ush* hwf       = (s & 1) ? h0f : h1f;
    const ush* hrb = (s & 1) ? h1b : h0b;
    ush* hwb       = (s & 1) ? h0b : h1b;
    k_step<<<grid, 512, 0, stream>>>(embbf, tokperm, plens, cnts, wptf, wptb,
                                     b_f, b_b, hrf, hwf, hrb, hwb, cf, cb, s);
  }
  k_pool<<<B_SAMP, 256, 0, stream>>>(h0f, h1f, h0b, pinv, lens, plen, pooled);
  k_final<<<B_SAMP, 256, 0, stream>>>(pooled, Wlin, blin, out);
}